// Round 1
// baseline (189.939 us; speedup 1.0000x reference)
//
#include <hip/hip_runtime.h>

#define NQ   12
#define DIM  4096
#define NL   4
#define BLK  256
#define SKEWSZ (DIM + DIM/32)

typedef unsigned short u16;
typedef unsigned int   u32;

// ---------- compile-time GF(2) linear algebra for the CNOT-chain permutation ----------
struct L12 { u16 b[NQ]; };

static constexpr u32 lap(const L12& A, u32 x){ u32 r=0; for(int p=0;p<NQ;++p) if((x>>p)&1u) r^=A.b[p]; return r; }
static constexpr L12 lcomp(const L12& A, const L12& B){ L12 r{}; for(int p=0;p<NQ;++p) r.b[p]=(u16)lap(A,(u32)B.b[p]); return r; } // A∘B
static constexpr L12 lident(){ L12 r{}; for(int p=0;p<NQ;++p) r.b[p]=(u16)(1u<<p); return r; }

// T(i): new_state[i] = old_state[T(i)] for one full CNOT block.
// Sequence applied to the state: C(0,1), C(1,2), ..., C(10,11), C(11,0).
// Index-space composition therefore applies g_{11,0} FIRST:
static constexpr u32 applyT(u32 i){
  i ^= ((i>>0)&1u) << 11;                            // CNOT(11,0): bit11 ^= bit0
  for(int q=10;q>=0;--q){ int pc=11-q, pt=10-q; i ^= ((i>>pc)&1u) << pt; }
  return i;
}
static constexpr L12 lT(){ L12 t{}; for(int p=0;p<NQ;++p) t.b[p]=(u16)applyT(1u<<p); return t; }

static constexpr L12 linv(const L12& A){              // GF(2) Gauss-Jordan
  u16 v[NQ]; u16 u[NQ];
  for(int p=0;p<NQ;++p){ v[p]=A.b[p]; u[p]=(u16)(1u<<p); }
  for(int t=0;t<NQ;++t){
    int p=t; while(!((v[p]>>t)&1u)) ++p;
    u16 tv=v[p]; v[p]=v[t]; v[t]=tv; u16 tu=u[p]; u[p]=u[t]; u[t]=tu;
    for(int k=0;k<NQ;++k) if(k!=t && ((v[k]>>t)&1u)){ v[k]^=v[t]; u[k]^=u[t]; }
  }
  L12 r{}; for(int p=0;p<NQ;++p) r.b[p]=u[p]; return r;
}
static constexpr L12 ltr(const L12& A){
  L12 r{}; for(int p=0;p<NQ;++p) for(int q=0;q<NQ;++q) if((A.b[p]>>q)&1u) r.b[q]=(u16)(r.b[q]|(1u<<p));
  return r;
}

struct Tables {
  u16 cm[12][16];   // [step][combo] xor-offsets spanning the 4 gate masks
  u16 wg[12][4];    // [step][gate] parity mask: a0/a1 role selector
  u16 sp[12][4];    // [step] sorted pivot bit positions (coset enumeration)
  u16 wexp[NQ];     // final <Z> parity masks: rows of (T^4)^{-T}
};

static constexpr Tables make_tables(){
  Tables tb{};
  const L12 T   = lT();
  const L12 Tit = ltr(linv(T));   // T^{-T}
  L12 A = lident();               // A_l = T^l   (stored_index = A_l(true_index))
  L12 W = lident();               // W_l = A_l^{-T}
  for(int l=0;l<NL;++l){
    for(int g=0;g<3;++g){
      const int st = l*3+g;
      u16 mm[4]={0,0,0,0};
      for(int i=0;i<4;++i){ mm[i]=A.b[4*g+i]; tb.wg[st][i]=W.b[4*g+i]; }
      u32 ech[4]={0,0,0,0}; int piv[4]={0,0,0,0};
      for(int i=0;i<4;++i){
        u32 v=mm[i];
        for(int k=0;k<i;++k) if((v>>piv[k])&1u) v^=ech[k];
        int t2=11; while(!((v>>t2)&1u)) --t2;
        piv[i]=t2; ech[i]=v;
      }
      for(int a2=0;a2<4;++a2) for(int b2=a2+1;b2<4;++b2)
        if(piv[b2]<piv[a2]){ int tt=piv[a2]; piv[a2]=piv[b2]; piv[b2]=tt; }
      for(int i=0;i<4;++i) tb.sp[st][i]=(u16)piv[i];
      for(int c=0;c<16;++c){ u32 m=0; for(int i=0;i<4;++i) if((c>>i)&1) m^=mm[i]; tb.cm[st][c]=(u16)m; }
    }
    A = lcomp(A, T);    // A_{l+1} = A_l ∘ T
    W = lcomp(W, Tit);  // W_{l+1} = W_l ∘ T^{-T}
  }
  for(int p=0;p<NQ;++p) tb.wexp[p]=W.b[p];
  return tb;
}

__device__ constexpr Tables TB = make_tables();

__device__ __forceinline__ int skew(int j){ return j + (j>>5); }   // break pow2 LDS strides
__device__ __forceinline__ u32 ins0(u32 v, u32 s){ return ((v>>s)<<(s+1)) | (v & ((1u<<s)-1u)); }
__device__ __forceinline__ float sxor(float a, u32 m){ return __uint_as_float(__float_as_uint(a)^m); }

__global__ __launch_bounds__(BLK) void qsim_kernel(const float* __restrict__ x,
                                                   const float* __restrict__ w,
                                                   float* __restrict__ out)
{
  __shared__ float sre[SKEWSZ];
  __shared__ float sim[SKEWSZ];
  __shared__ float gp[NL*NQ][4];   // per-gate: cos(ty/2), sin(ty/2), cos(tz/2), sin(tz/2)
  __shared__ float rnorm[4];
  __shared__ float wred[4][NQ];

  const int tid = threadIdx.x;
  const int bb  = blockIdx.x;
  const float* xr = x + (size_t)bb * DIM;

  // gate trig params (uniform across batch): gate index = st*4 + i = l*12 + p
  if (tid < NL*NQ) {
    const int l = tid / NQ, p = tid % NQ, q = (NQ-1) - p;
    const float ty = w[(l*NQ + q)*2 + 0];
    const float tz = w[(l*NQ + q)*2 + 1];
    float sy, cy, sz, cz;
    sincosf(0.5f*ty, &sy, &cy);
    sincosf(0.5f*tz, &sz, &cz);
    gp[tid][0]=cy; gp[tid][1]=sy; gp[tid][2]=cz; gp[tid][3]=sz;
  }

  // load row, compute norm, write normalized state to LDS
  float xv[16];
  float ss = 0.f;
#pragma unroll
  for (int s = 0; s < 4; ++s) {
    const float4 v = reinterpret_cast<const float4*>(xr)[s*BLK + tid];
    xv[4*s+0]=v.x; xv[4*s+1]=v.y; xv[4*s+2]=v.z; xv[4*s+3]=v.w;
    ss = fmaf(v.x,v.x, fmaf(v.y,v.y, fmaf(v.z,v.z, fmaf(v.w,v.w, ss))));
  }
#pragma unroll
  for (int o = 32; o; o >>= 1) ss += __shfl_xor(ss, o);
  if ((tid & 63) == 0) rnorm[tid>>6] = ss;
  __syncthreads();
  const float inv = rsqrtf(rnorm[0]+rnorm[1]+rnorm[2]+rnorm[3]);
#pragma unroll
  for (int s = 0; s < 4; ++s) {
#pragma unroll
    for (int k = 0; k < 4; ++k) {
      const int j = 4*(s*BLK + tid) + k;
      const int js = skew(j);
      sre[js] = xv[4*s+k]*inv;
      sim[js] = 0.f;
    }
  }
  __syncthreads();

  // 12 steps: 4 fused RZ·RY gates per step, CNOT blocks virtualized into the masks
#pragma unroll 1
  for (int st = 0; st < 12; ++st) {
    u32 rep = (u32)tid;
    rep = ins0(rep, TB.sp[st][0]);
    rep = ins0(rep, TB.sp[st][1]);
    rep = ins0(rep, TB.sp[st][2]);
    rep = ins0(rep, TB.sp[st][3]);

    float ar[16], ai[16];
    int ad[16];
#pragma unroll
    for (int c = 0; c < 16; ++c) {
      const int j  = (int)(rep ^ (u32)TB.cm[st][c]);
      const int js = skew(j);
      ad[c] = js;
      ar[c] = sre[js];
      ai[c] = sim[js];
    }
#pragma unroll
    for (int i = 0; i < 4; ++i) {
      const float cy = gp[st*4+i][0];
      const float cz = gp[st*4+i][2];
      // role flip folded into constants: s->-s, sin(tz/2)->-sin(tz/2)
      const u32 flip = ((u32)__popc((u32)rep & (u32)TB.wg[st][i]) & 1u) << 31;
      const float se = sxor(gp[st*4+i][1], flip);
      const float ze = sxor(gp[st*4+i][3], flip);
#pragma unroll
      for (int c = 0; c < 16; ++c) {
        if ((c >> i) & 1) continue;
        const int c1 = c | (1 << i);
        const float a0r=ar[c], a0i=ai[c], a1r=ar[c1], a1i=ai[c1];
        const float t0r = fmaf(cy,a0r, -se*a1r);
        const float t0i = fmaf(cy,a0i, -se*a1i);
        const float t1r = fmaf(se,a0r,  cy*a1r);
        const float t1i = fmaf(se,a0i,  cy*a1i);
        ar[c]  = fmaf(cz,t0r,  ze*t0i);   // slot0' = (cz - i ze) * t0
        ai[c]  = fmaf(cz,t0i, -ze*t0r);
        ar[c1] = fmaf(cz,t1r, -ze*t1i);   // slot1' = (cz + i ze) * t1
        ai[c1] = fmaf(cz,t1i,  ze*t1r);
      }
    }
#pragma unroll
    for (int c = 0; c < 16; ++c) { sre[ad[c]] = ar[c]; sim[ad[c]] = ai[c]; }
    __syncthreads();
  }

  // <Z_q> = sum_j |amp_j|^2 * (-1)^{bit_p(true index)},  bit = parity(j & wexp[p]), p = 11-q
  float acc[NQ];
#pragma unroll
  for (int q = 0; q < NQ; ++q) acc[q] = 0.f;
#pragma unroll
  for (int s = 0; s < 16; ++s) {
    const int j  = s*BLK + tid;
    const int js = skew(j);
    const float r = sre[js], m = sim[js];
    const float pr = fmaf(r,r, m*m);
#pragma unroll
    for (int q = 0; q < NQ; ++q) {
      const int p = (NQ-1) - q;
      const u32 sgn = ((u32)__popc((u32)j & (u32)TB.wexp[p]) & 1u) << 31;
      acc[q] += sxor(pr, sgn);
    }
  }
#pragma unroll
  for (int q = 0; q < NQ; ++q) {
#pragma unroll
    for (int o = 32; o; o >>= 1) acc[q] += __shfl_xor(acc[q], o);
  }
  const int wid = tid >> 6;
  if ((tid & 63) == 0) {
#pragma unroll
    for (int q = 0; q < NQ; ++q) wred[wid][q] = acc[q];
  }
  __syncthreads();
  if (tid < NQ) out[(size_t)bb*NQ + tid] = wred[0][tid]+wred[1][tid]+wred[2][tid]+wred[3][tid];
}

extern "C" void kernel_launch(void* const* d_in, const int* in_sizes, int n_in,
                              void* d_out, int out_size, void* d_ws, size_t ws_size,
                              hipStream_t stream) {
  const float* x = (const float*)d_in[0];
  const float* w = (const float*)d_in[1];
  float* out = (float*)d_out;
  const int B = in_sizes[0] / DIM;
  qsim_kernel<<<B, BLK, 0, stream>>>(x, w, out);
}

// Round 2
// 130.179 us; speedup vs baseline: 1.4591x; 1.4591x over previous
//
#include <hip/hip_runtime.h>

#define NQ   12
#define DIM  4096
#define NL   4
#define BLK  256

typedef unsigned short u16;
typedef unsigned int   u32;

// ---------- compile-time GF(2) linear algebra for the CNOT-chain permutation ----------
struct L12 { u16 b[NQ]; };

static constexpr u32 lap(const L12& A, u32 x){ u32 r=0; for(int p=0;p<NQ;++p) if((x>>p)&1u) r^=A.b[p]; return r; }
static constexpr L12 lcomp(const L12& A, const L12& B){ L12 r{}; for(int p=0;p<NQ;++p) r.b[p]=(u16)lap(A,(u32)B.b[p]); return r; } // A∘B
static constexpr L12 lident(){ L12 r{}; for(int p=0;p<NQ;++p) r.b[p]=(u16)(1u<<p); return r; }

static constexpr u32 applyT(u32 i){
  i ^= ((i>>0)&1u) << 11;                            // CNOT(11,0): bit11 ^= bit0
  for(int q=10;q>=0;--q){ int pc=11-q, pt=10-q; i ^= ((i>>pc)&1u) << pt; }
  return i;
}
static constexpr L12 lT(){ L12 t{}; for(int p=0;p<NQ;++p) t.b[p]=(u16)applyT(1u<<p); return t; }

static constexpr L12 linv(const L12& A){              // GF(2) Gauss-Jordan
  u16 v[NQ]; u16 u[NQ];
  for(int p=0;p<NQ;++p){ v[p]=A.b[p]; u[p]=(u16)(1u<<p); }
  for(int t=0;t<NQ;++t){
    int p=t; while(!((v[p]>>t)&1u)) ++p;
    u16 tv=v[p]; v[p]=v[t]; v[t]=tv; u16 tu=u[p]; u[p]=u[t]; u[t]=tu;
    for(int k=0;k<NQ;++k) if(k!=t && ((v[k]>>t)&1u)){ v[k]^=v[t]; u[k]^=u[t]; }
  }
  L12 r{}; for(int p=0;p<NQ;++p) r.b[p]=u[p]; return r;
}
static constexpr L12 ltr(const L12& A){
  L12 r{}; for(int p=0;p<NQ;++p) for(int q=0;q<NQ;++q) if((A.b[p]>>q)&1u) r.b[q]=(u16)(r.b[q]|(1u<<p));
  return r;
}

struct Tables {
  u16 cm[12][16];   // [step][combo] xor-offsets spanning the 4 gate masks
  u16 wg[12][4];    // [step][gate] parity mask: a0/a1 role selector
  u16 sp[12][4];    // [step] sorted pivot bit positions
  u16 wexp[NQ];     // final <Z> parity masks: rows of (T^4)^{-T}
};

static constexpr Tables make_tables(){
  Tables tb{};
  const L12 T   = lT();
  const L12 Tit = ltr(linv(T));   // T^{-T}
  L12 A = lident();               // A_l = T^l   (stored_index = A_l(true_index))
  L12 W = lident();               // W_l = A_l^{-T}
  for(int l=0;l<NL;++l){
    for(int g=0;g<3;++g){
      const int st = l*3+g;
      u16 mm[4]={0,0,0,0};
      for(int i=0;i<4;++i){ mm[i]=A.b[4*g+i]; tb.wg[st][i]=W.b[4*g+i]; }
      u32 ech[4]={0,0,0,0}; int piv[4]={0,0,0,0};
      for(int i=0;i<4;++i){
        u32 v=mm[i];
        for(int k=0;k<i;++k) if((v>>piv[k])&1u) v^=ech[k];
        int t2=11; while(!((v>>t2)&1u)) --t2;
        piv[i]=t2; ech[i]=v;
      }
      for(int a2=0;a2<4;++a2) for(int b2=a2+1;b2<4;++b2)
        if(piv[b2]<piv[a2]){ int tt=piv[a2]; piv[a2]=piv[b2]; piv[b2]=tt; }
      for(int i=0;i<4;++i) tb.sp[st][i]=(u16)piv[i];
      for(int c=0;c<16;++c){ u32 m=0; for(int i=0;i<4;++i) if((c>>i)&1) m^=mm[i]; tb.cm[st][c]=(u16)m; }
    }
    A = lcomp(A, T);
    W = lcomp(W, Tit);
  }
  for(int p=0;p<NQ;++p) tb.wexp[p]=W.b[p];
  return tb;
}

__device__ constexpr Tables TB = make_tables();

// ---------- LDS swizzle: slot = j ^ fold(j>>4), fold linear over GF(2) ----------
static constexpr u16 UIMG[12] = {1,2,4,8, 3,5,6,7, 9,10,11,13};  // bank-pair image of each bit position

static constexpr u32 swz(u32 j){
  u32 f=0;
  for(int k=4;k<12;++k) if((j>>k)&1u) f ^= (u32)UIMG[k];
  return j ^ (f & 15u);
}

struct Derived {
  u32 lane_c[12][8];  // tid bit k -> (swz(1<<pos)<<3) | (role-parity nibble <<28)
  u32 smb[12][4];     // swz(mask_i)<<3  (rep parity correction)
  u32 scmb[12][16];   // swz(cm[c])<<3   (coset member byte offsets)
  u32 eps[16];        // swz(s<<8)<<3    (init/epilogue per-s offsets)
  u32 tidc[8];        // swz(1<<k)<<3    (init/epilogue per-thread base)
  u16 esgn[12];       // compile-time readout sign bits over s
};

static constexpr Derived make_derived(){
  const Tables tb = make_tables();
  Derived d{};
  for(int st=0; st<12; ++st){
    bool isp[12]={false,false,false,false,false,false,false,false,false,false,false,false};
    for(int i=0;i<4;++i) isp[tb.sp[st][i]]=true;
    int np[8]; int nn=0;
    for(int p=0;p<12;++p) if(!isp[p]) np[nn++]=p;
    // choose 6 of 8 non-pivot positions for the wave's lane bits s.t. their
    // GF(2)^4 bank-pair images have rank 4 -> exactly 4 lanes per bank-pair (b64-free)
    int best=-1;
    for(int ms=0; ms<256; ++ms){
      int pc=0; for(int k=0;k<8;++k) pc+=(ms>>k)&1;
      if(pc!=6) continue;
      u16 bas[4]={0,0,0,0}; int r=0;
      for(int k=0;k<8;++k){
        if(!((ms>>k)&1)) continue;
        u16 x=(u16)(UIMG[np[k]]&15);
        while(x){
          int hb=3; while(!((x>>hb)&1)) --hb;
          if(bas[hb]) x=(u16)(x^bas[hb]);
          else { bas[hb]=x; ++r; x=0; }
        }
      }
      if(r==4){ best=ms; break; }
    }
    if(best<0) best=0x3F;
    int pos[8]; int lo=0, hi=6;
    for(int k=0;k<8;++k){ if((best>>k)&1) pos[lo++]=np[k]; else pos[hi++]=np[k]; }
    for(int k=0;k<8;++k){
      const u32 addr = swz(1u<<pos[k])<<3;
      u32 nib=0;
      for(int i=0;i<4;++i) nib |= (u32)((tb.wg[st][i]>>pos[k])&1u)<<i;
      d.lane_c[st][k] = addr | (nib<<28);
    }
    for(int i=0;i<4;++i)  d.smb[st][i]  = swz((u32)tb.cm[st][1<<i])<<3;
    for(int c=0;c<16;++c) d.scmb[st][c] = swz((u32)tb.cm[st][c])<<3;
  }
  for(int s=0;s<16;++s) d.eps[s]  = swz((u32)s<<8)<<3;
  for(int k=0;k<8;++k)  d.tidc[k] = swz(1u<<k)<<3;
  for(int q=0;q<12;++q){
    u16 m=0;
    for(int s=0;s<16;++s){
      int par=0; u32 v=((u32)s<<8) & (u32)tb.wexp[11-q];
      while(v){ par ^= (int)(v&1u); v>>=1; }
      m |= (u16)(par<<s);
    }
    d.esgn[q]=m;
  }
  return d;
}

__device__ constexpr Derived DV = make_derived();

// per-thread, per-step: swizzled byte base of the parity-corrected coset representative
__device__ __forceinline__ u32 step_base(int st, int tid){
  u32 acc=0;
#pragma unroll
  for(int k=0;k<8;++k) acc ^= DV.lane_c[st][k] & (0u-((u32)(tid>>k)&1u));
  const u32 nib = acc>>28;
  u32 b = acc & 0x0FFFFFFFu;
#pragma unroll
  for(int i=0;i<4;++i) b ^= DV.smb[st][i] & (0u-((nib>>i)&1u));
  return b;
}

// 4 commuting gates along virtualized axes; roles pre-aligned (no flips).
// Gate (global phase dropped): out0 = cy*a0 - sy*a1 ; out1 = (cw + i*sw)*(sy*a0 + cy*a1)
template<bool WITHW, bool FIRST>
__device__ __forceinline__ void do_step(int st, int tid, char* lds, const float4* gq){
  const u32 base = step_base(st, tid);
  u32 ad[16]; float ar[16], ai[16];
#pragma unroll
  for(int c=0;c<16;++c){
    ad[c] = base ^ DV.scmb[st][c];
    if(FIRST){ ar[c] = *(const float*)(lds + ad[c]); ai[c]=0.f; }
    else { const float2 v = *(const float2*)(lds + ad[c]); ar[c]=v.x; ai[c]=v.y; }
  }
#pragma unroll
  for(int i=0;i<4;++i){
    const float4 g = gq[st*4+i];   // {cy, sy, cw, sw}
#pragma unroll
    for(int c=0;c<16;++c){
      if((c>>i)&1) continue;
      const int c1 = c | (1<<i);
      const float a0r=ar[c], a0i=ai[c], a1r=ar[c1], a1i=ai[c1];
      const float t0r = fmaf(g.x,a0r, -(g.y*a1r));
      const float t0i = fmaf(g.x,a0i, -(g.y*a1i));
      const float t1r = fmaf(g.y,a0r,  g.x*a1r);
      const float t1i = fmaf(g.y,a0i,  g.x*a1i);
      ar[c]=t0r; ai[c]=t0i;
      if(WITHW){
        ar[c1] = fmaf(g.z,t1r, -(g.w*t1i));
        ai[c1] = fmaf(g.z,t1i,  g.w*t1r);
      } else { ar[c1]=t1r; ai[c1]=t1i; }
    }
  }
#pragma unroll
  for(int c=0;c<16;++c){ float2 v; v.x=ar[c]; v.y=ai[c]; *(float2*)(lds+ad[c]) = v; }
  __syncthreads();
}

__global__ __launch_bounds__(BLK) void qsim_kernel(const float* __restrict__ x,
                                                   const float* __restrict__ w,
                                                   float* __restrict__ out)
{
  __shared__ float2 st2[DIM];
  __shared__ float4 gq[NL*NQ];
  __shared__ float  wred[4][13];
  char* lds = (char*)st2;
  const int tid = threadIdx.x;
  const int bb  = blockIdx.x;

  // gate params (uniform across batch): {cos(ty/2), sin(ty/2), cos(tz), sin(tz)}
  if (tid < NL*NQ) {
    const int l = tid/NQ, p = tid%NQ, q = (NQ-1)-p;
    const float ty = w[(l*NQ+q)*2+0];
    const float tz = w[(l*NQ+q)*2+1];
    float sy,cy,szf,czf;
    sincosf(0.5f*ty, &sy, &cy);
    sincosf(tz, &szf, &czf);
    gq[tid] = make_float4(cy, sy, czf, szf);
  }

  u32 be=0;
#pragma unroll
  for(int k=0;k<8;++k) be ^= DV.tidc[k] & (0u-((u32)(tid>>k)&1u));

  // load raw row (normalization deferred to epilogue), write RE only (step 0 is real)
  const float* xr = x + (size_t)bb * DIM;
  float xv[16];
#pragma unroll
  for(int s=0;s<16;++s) xv[s] = xr[(s<<8)|tid];
#pragma unroll
  for(int s=0;s<16;++s) *(float*)(lds + (be ^ DV.eps[s])) = xv[s];
  __syncthreads();

  do_step<true,true>(0, tid, lds, gq);
#pragma unroll 1
  for(int st=1; st<9; ++st) do_step<true,false>(st, tid, lds, gq);
#pragma unroll 1
  for(int st=9; st<12; ++st) do_step<false,false>(st, tid, lds, gq);  // last layer: RZ dropped

  // readout: acc_q = sum_s ±pr[s] (compile-time signs) then one per-thread sign xor
  float pr[16]; float nrm=0.f;
#pragma unroll
  for(int s=0;s<16;++s){
    const float2 v = *(const float2*)(lds + (be ^ DV.eps[s]));
    pr[s] = fmaf(v.x,v.x, v.y*v.y);
    nrm += pr[s];
  }
  float accq[12];
#pragma unroll
  for(int q=0;q<12;++q){
    float a=0.f;
#pragma unroll
    for(int s=0;s<16;++s){
      if((DV.esgn[q]>>s)&1) a -= pr[s]; else a += pr[s];
    }
    const u32 b = ((u32)__popc((u32)tid & (u32)TB.wexp[11-q]) & 1u) << 31;
    accq[q] = __uint_as_float(__float_as_uint(a) ^ b);
  }
#pragma unroll
  for(int o=32;o;o>>=1){
    nrm += __shfl_xor(nrm,o);
#pragma unroll
    for(int q=0;q<12;++q) accq[q] += __shfl_xor(accq[q],o);
  }
  const int wid = tid>>6;
  if((tid&63)==0){
#pragma unroll
    for(int q=0;q<12;++q) wred[wid][q]=accq[q];
    wred[wid][12]=nrm;
  }
  __syncthreads();
  if(tid<NQ){
    const float s0 = wred[0][tid]+wred[1][tid]+wred[2][tid]+wred[3][tid];
    const float sn = wred[0][12]+wred[1][12]+wred[2][12]+wred[3][12];
    out[(size_t)bb*NQ + tid] = s0/sn;
  }
}

extern "C" void kernel_launch(void* const* d_in, const int* in_sizes, int n_in,
                              void* d_out, int out_size, void* d_ws, size_t ws_size,
                              hipStream_t stream) {
  const float* x = (const float*)d_in[0];
  const float* w = (const float*)d_in[1];
  float* out = (float*)d_out;
  const int B = in_sizes[0] / DIM;
  qsim_kernel<<<B, BLK, 0, stream>>>(x, w, out);
}

// Round 3
// 112.692 us; speedup vs baseline: 1.6855x; 1.1552x over previous
//
#include <hip/hip_runtime.h>

#define NQ   12
#define DIM  4096
#define NL   4
#define BLK  256

typedef unsigned short u16;
typedef unsigned int   u32;

// ---------- compile-time GF(2) linear algebra for the CNOT-chain permutation ----------
struct L12 { u16 b[NQ]; };

static constexpr u32 lap(const L12& A, u32 x){ u32 r=0; for(int p=0;p<NQ;++p) if((x>>p)&1u) r^=A.b[p]; return r; }
static constexpr L12 lcomp(const L12& A, const L12& B){ L12 r{}; for(int p=0;p<NQ;++p) r.b[p]=(u16)lap(A,(u32)B.b[p]); return r; }
static constexpr L12 lident(){ L12 r{}; for(int p=0;p<NQ;++p) r.b[p]=(u16)(1u<<p); return r; }

static constexpr u32 applyT(u32 i){
  i ^= ((i>>0)&1u) << 11;                            // CNOT(11,0): bit11 ^= bit0
  for(int q=10;q>=0;--q){ int pc=11-q, pt=10-q; i ^= ((i>>pc)&1u) << pt; }
  return i;
}
static constexpr L12 lT(){ L12 t{}; for(int p=0;p<NQ;++p) t.b[p]=(u16)applyT(1u<<p); return t; }

static constexpr L12 linv(const L12& A){              // GF(2) Gauss-Jordan
  u16 v[NQ]; u16 u[NQ];
  for(int p=0;p<NQ;++p){ v[p]=A.b[p]; u[p]=(u16)(1u<<p); }
  for(int t=0;t<NQ;++t){
    int p=t; while(!((v[p]>>t)&1u)) ++p;
    u16 tv=v[p]; v[p]=v[t]; v[t]=tv; u16 tu=u[p]; u[p]=u[t]; u[t]=tu;
    for(int k=0;k<NQ;++k) if(k!=t && ((v[k]>>t)&1u)){ v[k]^=v[t]; u[k]^=u[t]; }
  }
  L12 r{}; for(int p=0;p<NQ;++p) r.b[p]=u[p]; return r;
}
static constexpr L12 ltr(const L12& A){
  L12 r{}; for(int p=0;p<NQ;++p) for(int q=0;q<NQ;++q) if((A.b[p]>>q)&1u) r.b[q]=(u16)(r.b[q]|(1u<<p));
  return r;
}
static constexpr int cpop(u32 v){ int n=0; while(v){ n+=(int)(v&1u); v>>=1; } return n; }

struct Tables {
  u16 cm[12][16];   // [step][combo] xor-offsets spanning the 4 gate masks
  u16 wg[12][4];    // [step][gate] parity mask: a0/a1 role selector
  u16 sp[12][4];    // [step] sorted pivot bit positions
  u16 wexp[NQ];     // final <Z> parity masks: rows of (T^4)^{-T}
};

static constexpr Tables make_tables(){
  Tables tb{};
  const L12 T   = lT();
  const L12 Tit = ltr(linv(T));   // T^{-T}
  L12 A = lident();               // A_l = T^l   (stored_index = A_l(true_index))
  L12 W = lident();               // W_l = A_l^{-T}
  for(int l=0;l<NL;++l){
    for(int g=0;g<3;++g){
      const int st = l*3+g;
      u16 mm[4]={0,0,0,0};
      for(int i=0;i<4;++i){ mm[i]=A.b[4*g+i]; tb.wg[st][i]=W.b[4*g+i]; }
      u32 ech[4]={0,0,0,0}; int piv[4]={0,0,0,0};
      for(int i=0;i<4;++i){
        u32 v=mm[i];
        for(int k=0;k<i;++k) if((v>>piv[k])&1u) v^=ech[k];
        int t2=11; while(!((v>>t2)&1u)) --t2;
        piv[i]=t2; ech[i]=v;
      }
      for(int a2=0;a2<4;++a2) for(int b2=a2+1;b2<4;++b2)
        if(piv[b2]<piv[a2]){ int tt=piv[a2]; piv[a2]=piv[b2]; piv[b2]=tt; }
      for(int i=0;i<4;++i) tb.sp[st][i]=(u16)piv[i];
      for(int c=0;c<16;++c){ u32 m=0; for(int i=0;i<4;++i) if((c>>i)&1) m^=mm[i]; tb.cm[st][c]=(u16)m; }
    }
    A = lcomp(A, T);
    W = lcomp(W, Tit);
  }
  for(int p=0;p<NQ;++p) tb.wexp[p]=W.b[p];
  return tb;
}

__device__ constexpr Tables TB = make_tables();

// ---------- LDS swizzle: slot = j ^ fold(j>>4), fold linear over GF(2) ----------
static constexpr u16 UIMG[12] = {1,2,4,8, 3,5,6,7, 9,10,11,13};

static constexpr u32 swz(u32 j){
  u32 f=0;
  for(int k=4;k<12;++k) if((j>>k)&1u) f ^= (u32)UIMG[k];
  return j ^ (f & 15u);
}

struct Derived {
  u32 lane_c[12][8];  // tid bit k -> (swz(1<<pos)<<3) | (role-parity nibble <<28)
  u32 smb[12][4];     // swz(cm[1<<i])<<3  (rep parity correction, swizzled)
  u32 scmb[12][16];   // swz(cm[c])<<3     (coset member byte offsets)
  u32 g0lane[8];      // step 0: unswizzled element-index contribution of tid bit k
  u32 u11lane[8];     // step 11: unswizzled index contribution of tid bit k
  u32 u11smb[4];      // step 11: unswizzled cm[1<<i]
  u16 csgn[12];       // per output q: compile-time sign bits over combo c at step 11
  u16 pm[12];         // wexp[11-q]: per-thread parity mask on unswizzled rep
};

static constexpr Derived make_derived(){
  const Tables tb = make_tables();
  Derived d{};
  for(int st=0; st<12; ++st){
    bool isp[12]={false,false,false,false,false,false,false,false,false,false,false,false};
    for(int i=0;i<4;++i) isp[tb.sp[st][i]]=true;
    int np[8]; int nn=0;
    for(int p=0;p<12;++p) if(!isp[p]) np[nn++]=p;
    // choose 6 of 8 non-pivot positions for lane bits s.t. their GF(2)^4
    // bank-pair images have rank 4 -> exactly 4 lanes/bank-pair (b64 floor)
    int best=-1;
    for(int ms=0; ms<256; ++ms){
      int pc=0; for(int k=0;k<8;++k) pc+=(ms>>k)&1;
      if(pc!=6) continue;
      u16 bas[4]={0,0,0,0}; int r=0;
      for(int k=0;k<8;++k){
        if(!((ms>>k)&1)) continue;
        u16 x=(u16)(UIMG[np[k]]&15);
        while(x){
          int hb=3; while(!((x>>hb)&1)) --hb;
          if(bas[hb]) x=(u16)(x^bas[hb]);
          else { bas[hb]=x; ++r; x=0; }
        }
      }
      if(r==4){ best=ms; break; }
    }
    if(best<0) best=0x3F;
    int pos[8]; int lo=0, hi=6;
    for(int k=0;k<8;++k){ if((best>>k)&1) pos[lo++]=np[k]; else pos[hi++]=np[k]; }
    for(int k=0;k<8;++k){
      const u32 addr = swz(1u<<pos[k])<<3;
      u32 nib=0;
      for(int i=0;i<4;++i) nib |= (u32)((tb.wg[st][i]>>pos[k])&1u)<<i;
      d.lane_c[st][k] = addr | (nib<<28);
      if(st==0)  d.g0lane[k]  = 1u<<pos[k];
      if(st==11) d.u11lane[k] = 1u<<pos[k];
    }
    for(int i=0;i<4;++i)  d.smb[st][i]  = swz((u32)tb.cm[st][1<<i])<<3;
    for(int c=0;c<16;++c) d.scmb[st][c] = swz((u32)tb.cm[st][c])<<3;
    if(st==11) for(int i=0;i<4;++i) d.u11smb[i] = (u32)tb.cm[11][1<<i];
  }
  for(int q=0;q<12;++q){
    d.pm[q] = tb.wexp[11-q];
    u16 m=0;
    for(int c=0;c<16;++c){
      const int par = cpop((u32)tb.cm[11][c] & (u32)tb.wexp[11-q]) & 1;
      m |= (u16)(par<<c);
    }
    d.csgn[q]=m;
  }
  return d;
}

__device__ constexpr Derived DV = make_derived();

// ---------- 4 commuting gates via 3-shear rotations (all-FMA) ----------
// RY(ty) part on (a0,a1): t=tan(ty/4), s=sin(ty/2);  RZ phase on a1: t=tan(tz/2), s=sin(tz)
template<int ST, bool WITHW>
__device__ __forceinline__ void gates(float (&ar)[16], float (&ai)[16], const float4* __restrict__ gw){
#pragma unroll
  for(int i=0;i<4;++i){
    const float4 g = gw[ST*4+i];   // {tan(ty/4), sin(ty/2), tan(tz/2), sin(tz)}
#pragma unroll
    for(int c=0;c<16;++c){
      if((c>>i)&1) continue;
      const int c1 = c|(1<<i);
      float ur = fmaf(-g.x, ar[c1], ar[c]);     // u  = a0 - t*a1
      float ui = fmaf(-g.x, ai[c1], ai[c]);
      float vr = fmaf( g.y, ur, ar[c1]);        // a1' = a1 + s*u
      float vi = fmaf( g.y, ui, ai[c1]);
      ar[c] = fmaf(-g.x, vr, ur);               // a0' = u - t*a1'
      ai[c] = fmaf(-g.x, vi, ui);
      if(WITHW){                                // rotate (vr,vi) by +tz
        const float t = fmaf(-g.z, vi, vr);
        vi = fmaf( g.w, t, vi);
        vr = fmaf(-g.z, vi, t);
      }
      ar[c1]=vr; ai[c1]=vi;
    }
  }
}

template<int ST, bool WITHW>
__device__ __forceinline__ void mid_step(const u32* msk, char* lds, const float4* __restrict__ gw){
  u32 acc=0;
#pragma unroll
  for(int k=0;k<8;++k) acc ^= DV.lane_c[ST][k]&msk[k];
  const u32 nib = acc>>28;
  u32 base = acc & 0x0FFFFFFFu;
#pragma unroll
  for(int i=0;i<4;++i) base ^= DV.smb[ST][i] & (0u-((nib>>i)&1u));
  u32 ad[16]; float ar[16], ai[16];
#pragma unroll
  for(int c=0;c<16;++c){
    ad[c] = base ^ DV.scmb[ST][c];
    const float2 v = *(const float2*)(lds+ad[c]);
    ar[c]=v.x; ai[c]=v.y;
  }
  gates<ST,WITHW>(ar,ai,gw);
#pragma unroll
  for(int c=0;c<16;++c){ float2 v; v.x=ar[c]; v.y=ai[c]; *(float2*)(lds+ad[c])=v; }
  __syncthreads();
}

__global__ void prep_kernel(const float* __restrict__ w, float4* __restrict__ gw){
  const int t = threadIdx.x;
  if(t < NL*NQ){
    const int l=t/NQ, p=t%NQ, q=(NQ-1)-p;
    const float ty=w[(l*NQ+q)*2+0], tz=w[(l*NQ+q)*2+1];
    gw[t]=make_float4(tanf(0.25f*ty), sinf(0.5f*ty), tanf(0.5f*tz), sinf(tz));
  }
}

__global__ __launch_bounds__(BLK, 4) void qsim_kernel(const float* __restrict__ x,
                                                      const float4* __restrict__ gw,
                                                      float* __restrict__ out)
{
  __shared__ float2 st2[DIM];
  __shared__ float  wred[4][13];
  char* lds = (char*)st2;
  const int tid = threadIdx.x;
  const int bb  = blockIdx.x;

  u32 msk[8];
#pragma unroll
  for(int k=0;k<8;++k) msk[k]=0u-((u32)(tid>>k)&1u);

  // ---- step 0: masks are bits 0..3 -> coset = 16 consecutive floats in global ----
  u32 rep0=0, acc0=0;
#pragma unroll
  for(int k=0;k<8;++k){ rep0 ^= DV.g0lane[k]&msk[k]; acc0 ^= DV.lane_c[0][k]&msk[k]; }
  const u32 base0 = acc0 & 0x0FFFFFFFu;   // nib == 0 at step 0

  float ar[16], ai[16];
  const float* xr = x + (size_t)bb*DIM + rep0;
#pragma unroll
  for(int s=0;s<4;++s){
    const float4 v = *reinterpret_cast<const float4*>(xr + 4*s);
    ar[4*s+0]=v.x; ar[4*s+1]=v.y; ar[4*s+2]=v.z; ar[4*s+3]=v.w;
    ai[4*s+0]=0.f; ai[4*s+1]=0.f; ai[4*s+2]=0.f; ai[4*s+3]=0.f;
  }
  gates<0,true>(ar,ai,gw);
#pragma unroll
  for(int c=0;c<16;++c){ float2 v; v.x=ar[c]; v.y=ai[c];
    *(float2*)(lds + (base0 ^ DV.scmb[0][c])) = v; }
  __syncthreads();

  // ---- steps 1..10: LDS round trips ----
  mid_step<1,true >(msk,lds,gw);
  mid_step<2,true >(msk,lds,gw);
  mid_step<3,true >(msk,lds,gw);
  mid_step<4,true >(msk,lds,gw);
  mid_step<5,true >(msk,lds,gw);
  mid_step<6,true >(msk,lds,gw);
  mid_step<7,true >(msk,lds,gw);
  mid_step<8,true >(msk,lds,gw);
  mid_step<9,false>(msk,lds,gw);     // last layer: RZ phase dropped (|amp|^2 readout)
  mid_step<10,false>(msk,lds,gw);

  // ---- step 11 + fused readout (no write-back) ----
  {
    u32 acc=0, urep=0;
#pragma unroll
    for(int k=0;k<8;++k){ acc ^= DV.lane_c[11][k]&msk[k]; urep ^= DV.u11lane[k]&msk[k]; }
    const u32 nib = acc>>28;
    u32 base = acc & 0x0FFFFFFFu;
#pragma unroll
    for(int i=0;i<4;++i){ const u32 mi=0u-((nib>>i)&1u); base ^= DV.smb[11][i]&mi; urep ^= DV.u11smb[i]&mi; }
#pragma unroll
    for(int c=0;c<16;++c){
      const float2 v = *(const float2*)(lds + (base ^ DV.scmb[11][c]));
      ar[c]=v.x; ai[c]=v.y;
    }
    gates<11,false>(ar,ai,gw);

    float pr[16]; float nrm=0.f;
#pragma unroll
    for(int c=0;c<16;++c) pr[c]=fmaf(ar[c],ar[c], ai[c]*ai[c]);
#pragma unroll
    for(int c=0;c<16;++c) nrm += pr[c];
    float accq[12];
#pragma unroll
    for(int q=0;q<12;++q){
      float a=0.f;
#pragma unroll
      for(int c=0;c<16;++c){ if((DV.csgn[q]>>c)&1) a-=pr[c]; else a+=pr[c]; }
      const u32 sb = ((u32)__popc(urep & (u32)DV.pm[q]) & 1u)<<31;
      accq[q]=__uint_as_float(__float_as_uint(a)^sb);
    }
#pragma unroll
    for(int o=32;o;o>>=1){
      nrm += __shfl_xor(nrm,o);
#pragma unroll
      for(int q=0;q<12;++q) accq[q]+=__shfl_xor(accq[q],o);
    }
    const int wid=tid>>6;
    if((tid&63)==0){
#pragma unroll
      for(int q=0;q<12;++q) wred[wid][q]=accq[q];
      wred[wid][12]=nrm;
    }
    __syncthreads();
    if(tid<NQ){
      const float s0=wred[0][tid]+wred[1][tid]+wred[2][tid]+wred[3][tid];
      const float sn=wred[0][12]+wred[1][12]+wred[2][12]+wred[3][12];
      out[(size_t)bb*NQ+tid]=s0/sn;
    }
  }
}

extern "C" void kernel_launch(void* const* d_in, const int* in_sizes, int n_in,
                              void* d_out, int out_size, void* d_ws, size_t ws_size,
                              hipStream_t stream) {
  const float* x = (const float*)d_in[0];
  const float* w = (const float*)d_in[1];
  float* out = (float*)d_out;
  float4* gw = (float4*)d_ws;
  const int B = in_sizes[0] / DIM;
  prep_kernel<<<1, 64, 0, stream>>>(w, gw);
  qsim_kernel<<<B, BLK, 0, stream>>>(x, gw, out);
}